// Round 11
// baseline (826.550 us; speedup 1.0000x reference)
//
#include <hip/hip_runtime.h>
#include <math.h>

// InstantNGP-style hash-grid encoder, 16 levels, FEAT=2, B=2M points.
//   dense levels 0..4 (res^3 <= 2^19), hashed levels 5..15 (size = 2^19 each)
//
// Measured cost laws (r3-r10):
//   L1: divergent gathers ~127 cyc per wave-instruction per CU (~1.5x at 16B)
//       WHILE the table is on-die (L1/L2/L3 equivalent); off-die adds 64B/lane
//       HBM line fills (killed r2/r10).
//   L2: exec-masking / payload width <8B give no discount.
//   L3: fusing gathers+streaming has ~30us penalty vs separate, worth it only
//       when it deletes a full streaming pass.
// Structure:
//   - convert_quad_kernel: Q[j] = bf16x2{T[j],T[j+1],T[j+res],T[j+res+1]}
//   - 5x dense_level_kernel<L>: per-level Q slice L2-fit, 2x16B gathers/pt
//   - 10x fine_level_kernel (levels 5..14): proven 51.6us config
//   - merge_final_kernel: level 15 inline (8x8B gathers, 4MB slice L2-fit)
//     + merge dws/fws -> [B,32] out. Streaming overlaps level-15 TA.
#define NLEVELS 16
#define BEGIN_FAST 5
#define P2 2654435761u
#define P3 805459861u
#define FAST_MASK 524287u
#define DENSE_TOTAL 330952u

constexpr unsigned kRes[NLEVELS] = {16u, 23u, 31u, 43u, 59u, 81u, 112u, 154u, 213u, 295u, 407u, 562u, 777u, 1073u, 1483u, 2048u};
constexpr unsigned kSize[NLEVELS] = {
    4096u, 12168u, 29792u, 79512u, 205384u,
    524288u, 524288u, 524288u, 524288u, 524288u, 524288u,
    524288u, 524288u, 524288u, 524288u, 524288u};
constexpr unsigned kOffset[NLEVELS] = {
    0u,       4096u,    16264u,   46056u,   125568u,  330952u,
    855240u,  1379528u, 1903816u, 2428104u, 2952392u, 3476680u,
    4000968u, 4525256u, 5049544u, 5573832u};

struct Scales {
    float s[NLEVELS];
};

typedef float fvec2 __attribute__((ext_vector_type(2)));
typedef float fvec4 __attribute__((ext_vector_type(4)));
typedef unsigned uvec4 __attribute__((ext_vector_type(4)));

// pack two f32 -> bf16x2 (round-to-nearest-even), lo = a, hi = b
__device__ __forceinline__ unsigned bfpack(float a, float b) {
    unsigned ua = __float_as_uint(a);
    unsigned ub = __float_as_uint(b);
    ua = (ua + 0x7FFFu + ((ua >> 16) & 1u)) >> 16;
    ub = (ub + 0x7FFFu + ((ub >> 16) & 1u)) & 0xFFFF0000u;
    return ua | ub;
}
__device__ __forceinline__ float bf_lo(unsigned e) { return __uint_as_float(e << 16); }
__device__ __forceinline__ float bf_hi(unsigned e) { return __uint_as_float(e & 0xFFFF0000u); }

// ---- dense quad table: Q[j] = bf16x2 of T[j], T[j+1], T[j+res], T[j+res+1] --
__global__ __launch_bounds__(256) void convert_quad_kernel(
    const float2* __restrict__ table,
    uvec4* __restrict__ Q,
    int total)
{
    int j = blockIdx.x * 256 + threadIdx.x;
    if (j >= total) return;
    int l = 0;
    if (j >= (int)kOffset[1]) l = 1;
    if (j >= (int)kOffset[2]) l = 2;
    if (j >= (int)kOffset[3]) l = 3;
    if (j >= (int)kOffset[4]) l = 4;
    const unsigned size = kSize[l];
    const unsigned res = kRes[l];
    const unsigned jl = (unsigned)j - kOffset[l];
    unsigned j1 = jl + 1u;        if (j1 >= size) j1 -= size;
    unsigned jy = jl + res;       if (jy >= size) jy -= size;
    unsigned jy1 = jy + 1u;       if (jy1 >= size) jy1 -= size;
    const float2 t0 = table[kOffset[l] + jl];
    const float2 t1 = table[kOffset[l] + j1];
    const float2 t2 = table[kOffset[l] + jy];
    const float2 t3 = table[kOffset[l] + jy1];
    uvec4 r = {bfpack(t0.x, t0.y), bfpack(t1.x, t1.y),
               bfpack(t2.x, t2.y), bfpack(t3.x, t3.y)};
    __builtin_nontemporal_store(r, Q + j);
}

// ---------------- fine (hashed) level: EXACT proven 51.6us config ------------
__global__ __launch_bounds__(256) void fine_level_kernel(
    const float* __restrict__ positions,
    const float2* __restrict__ tab,       // f32 table + level offset
    float2* __restrict__ wsl,             // ws slice [B], float2
    int B, float s)
{
    int p = blockIdx.x * 256 + threadIdx.x;
    if (p >= B) return;

    const float x = __builtin_nontemporal_load(positions + 3 * p + 0);
    const float y = __builtin_nontemporal_load(positions + 3 * p + 1);
    const float z = __builtin_nontemporal_load(positions + 3 * p + 2);

    const float px = x * s + 0.5f;
    const float py = y * s + 0.5f;
    const float pz = z * s + 0.5f;
    const float flx = floorf(px), fly = floorf(py), flz = floorf(pz);
    const float rx = px - flx, ry = py - fly, rz = pz - flz;
    const unsigned gx = (unsigned)flx;
    const unsigned gy = (unsigned)fly;
    const unsigned gz = (unsigned)flz;
    const float wx0 = 1.0f - rx, wy0 = 1.0f - ry, wz0 = 1.0f - rz;

    const unsigned hy0 = gy * P2, hy1 = hy0 + P2;
    const unsigned hz0 = gz * P3, hz1 = hz0 + P3;

    float ax = 0.0f, ay = 0.0f;
#pragma unroll
    for (int c = 0; c < 8; ++c) {
        const unsigned cx = (unsigned)(c & 1);
        const unsigned cy = (unsigned)((c >> 1) & 1);
        const unsigned cz = (unsigned)((c >> 2) & 1);
        const float w = (cx ? rx : wx0) * (cy ? ry : wy0) * (cz ? rz : wz0);
        const unsigned h = (gx + cx) ^ (cy ? hy1 : hy0) ^ (cz ? hz1 : hz0);
        const float2 t = tab[h & FAST_MASK];
        ax += w * t.x;
        ay += w * t.y;
    }
    fvec2 r = {ax, ay};
    __builtin_nontemporal_store(r, reinterpret_cast<fvec2*>(wsl) + p);
}

// ---- dense level L: per-level Q slice (L2-fit), 2x 16B gathers/pt -----------
template<int L>
__global__ __launch_bounds__(256) void dense_level_kernel(
    const float* __restrict__ positions,
    const uvec4* __restrict__ Qs,        // Q + kOffset[L]
    unsigned* __restrict__ dwsl,         // dws slice [B], bf16x2
    int B, float s)
{
    int p = blockIdx.x * 256 + threadIdx.x;
    if (p >= B) return;

    const float x = __builtin_nontemporal_load(positions + 3 * p + 0);
    const float y = __builtin_nontemporal_load(positions + 3 * p + 1);
    const float z = __builtin_nontemporal_load(positions + 3 * p + 2);

    const float px = x * s + 0.5f;
    const float py = y * s + 0.5f;
    const float pz = z * s + 0.5f;
    const float flx = floorf(px), fly = floorf(py), flz = floorf(pz);
    const float rx = px - flx, ry = py - fly, rz = pz - flz;
    const unsigned gx = (unsigned)flx;
    const unsigned gy = (unsigned)fly;
    const unsigned gz = (unsigned)flz;
    const float wx0 = 1.0f - rx, wy0 = 1.0f - ry, wz0 = 1.0f - rz;

    const unsigned res = kRes[L];
    const unsigned res2 = res * res;
    const unsigned h0 = gx + gy * res + gz * res2;

    float ax = 0.0f, ay = 0.0f;
#pragma unroll
    for (int cz = 0; cz < 2; ++cz) {
        const float wz = cz ? rz : wz0;
        const unsigned idx = (h0 + (unsigned)cz * res2) % kSize[L];
        const uvec4 q = Qs[idx];   // 16B gather: 4 (cx,cy) corners
        ax += wz * (wy0 * (wx0 * bf_lo(q.x) + rx * bf_lo(q.y)) +
                    ry  * (wx0 * bf_lo(q.z) + rx * bf_lo(q.w)));
        ay += wz * (wy0 * (wx0 * bf_hi(q.x) + rx * bf_hi(q.y)) +
                    ry  * (wx0 * bf_hi(q.z) + rx * bf_hi(q.w)));
    }
    __builtin_nontemporal_store(bfpack(ax, ay), dwsl + p);
}

// ---- final: level 15 inline (8x 8B gathers) + merge dws/fws -> out ----------
__global__ __launch_bounds__(256) void merge_final_kernel(
    const float* __restrict__ positions,
    const float2* __restrict__ tab15,     // f32 table + kOffset[15]
    const unsigned* __restrict__ dws,     // [5][B] bf16x2 (levels 0..4)
    const float2* __restrict__ fws,       // [10][B] float2 (levels 5..14)
    float* __restrict__ out,              // [B,32]
    int B, float s15)
{
    const int p = blockIdx.x * 256 + threadIdx.x;
    if (p >= B) return;

    const float x = __builtin_nontemporal_load(positions + 3 * p + 0);
    const float y = __builtin_nontemporal_load(positions + 3 * p + 1);
    const float z = __builtin_nontemporal_load(positions + 3 * p + 2);

    // ---- level 15 gathers first (longest latency, overlap with streams) ----
    const float px = x * s15 + 0.5f;
    const float py = y * s15 + 0.5f;
    const float pz = z * s15 + 0.5f;
    const float flx = floorf(px), fly = floorf(py), flz = floorf(pz);
    const float rx = px - flx, ry = py - fly, rz = pz - flz;
    const unsigned gx = (unsigned)flx;
    const unsigned gy = (unsigned)fly;
    const unsigned gz = (unsigned)flz;
    const float wx0 = 1.0f - rx, wy0 = 1.0f - ry, wz0 = 1.0f - rz;
    const unsigned hy0 = gy * P2, hy1 = hy0 + P2;
    const unsigned hz0 = gz * P3, hz1 = hz0 + P3;

    float a15x = 0.0f, a15y = 0.0f;
#pragma unroll
    for (int c = 0; c < 8; ++c) {
        const unsigned cx = (unsigned)(c & 1);
        const unsigned cy = (unsigned)((c >> 1) & 1);
        const unsigned cz = (unsigned)((c >> 2) & 1);
        const float w = (cx ? rx : wx0) * (cy ? ry : wy0) * (cz ? rz : wz0);
        const unsigned h = (gx + cx) ^ (cy ? hy1 : hy0) ^ (cz ? hz1 : hz0);
        const float2 t = tab15[h & FAST_MASK];
        a15x += w * t.x;
        a15y += w * t.y;
    }

    float o[2 * NLEVELS];
#pragma unroll
    for (int l = 0; l < BEGIN_FAST; ++l) {
        const unsigned v = __builtin_nontemporal_load(dws + (size_t)l * (size_t)B + p);
        o[2 * l + 0] = bf_lo(v);
        o[2 * l + 1] = bf_hi(v);
    }
#pragma unroll
    for (int l = BEGIN_FAST; l < NLEVELS - 1; ++l) {
        const fvec2 v = __builtin_nontemporal_load(
            reinterpret_cast<const fvec2*>(fws) + (size_t)(l - BEGIN_FAST) * (size_t)B + p);
        o[2 * l + 0] = v.x;
        o[2 * l + 1] = v.y;
    }
    o[30] = a15x;
    o[31] = a15y;

    float* op = out + (size_t)p * (2 * NLEVELS);
#pragma unroll
    for (int i = 0; i < 8; ++i) {
        fvec4 v = {o[4 * i + 0], o[4 * i + 1], o[4 * i + 2], o[4 * i + 3]};
        *(reinterpret_cast<fvec4*>(op) + i) = v;
    }
}

// ---------------- fallback: monolithic f32 (if ws too small) -----------------
__global__ __launch_bounds__(256) void hash_encode_kernel(
    const float* __restrict__ positions,
    const float2* __restrict__ table,
    float* __restrict__ out,
    int B, Scales sc)
{
    int p = blockIdx.x * 256 + threadIdx.x;
    if (p >= B) return;

    const float x = positions[3 * p + 0];
    const float y = positions[3 * p + 1];
    const float z = positions[3 * p + 2];

    float o[2 * NLEVELS];

#pragma unroll
    for (int l = 0; l < NLEVELS; ++l) {
        const float s = sc.s[l];
        const float px = x * s + 0.5f;
        const float py = y * s + 0.5f;
        const float pz = z * s + 0.5f;
        const float flx = floorf(px), fly = floorf(py), flz = floorf(pz);
        const float rx = px - flx, ry = py - fly, rz = pz - flz;
        const unsigned gx = (unsigned)flx;
        const unsigned gy = (unsigned)fly;
        const unsigned gz = (unsigned)flz;
        const float wx0 = 1.0f - rx, wy0 = 1.0f - ry, wz0 = 1.0f - rz;

        float ax = 0.0f, ay = 0.0f;
#pragma unroll
        for (int c = 0; c < 8; ++c) {
            const unsigned cx = (unsigned)(c & 1);
            const unsigned cy = (unsigned)((c >> 1) & 1);
            const unsigned cz = (unsigned)((c >> 2) & 1);
            const unsigned pgx = gx + cx;
            const unsigned pgy = gy + cy;
            const unsigned pgz = gz + cz;
            const float w = (cx ? rx : wx0) * (cy ? ry : wy0) * (cz ? rz : wz0);
            unsigned h;
            if (l < BEGIN_FAST) {
                h = pgx + pgy * kRes[l] + pgz * (kRes[l] * kRes[l]);
            } else {
                h = pgx ^ (pgy * P2) ^ (pgz * P3);
            }
            const unsigned idx = (h % kSize[l]) + kOffset[l];
            const float2 t = table[idx];
            ax += w * t.x;
            ay += w * t.y;
        }
        o[2 * l + 0] = ax;
        o[2 * l + 1] = ay;
    }

    float* op = out + (size_t)p * (2 * NLEVELS);
#pragma unroll
    for (int i = 0; i < 8; ++i) {
        fvec4 v = {o[4 * i + 0], o[4 * i + 1], o[4 * i + 2], o[4 * i + 3]};
        *(reinterpret_cast<fvec4*>(op) + i) = v;
    }
}

extern "C" void kernel_launch(void* const* d_in, const int* in_sizes, int n_in,
                              void* d_out, int out_size, void* d_ws, size_t ws_size,
                              hipStream_t stream) {
    const float* positions = (const float*)d_in[0];
    const float2* table = (const float2*)d_in[1];
    float* out = (float*)d_out;

    const int B = in_sizes[0] / 3;

    Scales sc;
    const double log_b = log(2048.0 / 16.0) / (NLEVELS - 1);
    for (int l = 0; l < NLEVELS; ++l) {
        sc.s[l] = (float)(16.0 * exp((double)l * log_b) - 1.0);
    }

    const int blocks = (B + 255) / 256;

    // ws layout: [5 dense slices u32][10 fine slices float2][quad table Q]
    const size_t dws_bytes = 5u * (size_t)B * sizeof(unsigned);       // 40 MB
    const size_t fws_bytes = 10u * (size_t)B * sizeof(float2);        // 160 MB
    const size_t Q_bytes = (size_t)DENSE_TOTAL * sizeof(uvec4);       // 5.3 MB
    const size_t ws_need = dws_bytes + fws_bytes + Q_bytes;

    if (ws_size >= ws_need) {
        unsigned* dws = (unsigned*)d_ws;
        float2* fws = (float2*)((char*)d_ws + dws_bytes);
        uvec4* Q = (uvec4*)((char*)d_ws + dws_bytes + fws_bytes);

        convert_quad_kernel<<<((int)DENSE_TOTAL + 255) / 256, 256, 0, stream>>>(
            table, Q, (int)DENSE_TOTAL);

        dense_level_kernel<0><<<blocks, 256, 0, stream>>>(positions, Q + kOffset[0], dws + 0 * (size_t)B, B, sc.s[0]);
        dense_level_kernel<1><<<blocks, 256, 0, stream>>>(positions, Q + kOffset[1], dws + 1 * (size_t)B, B, sc.s[1]);
        dense_level_kernel<2><<<blocks, 256, 0, stream>>>(positions, Q + kOffset[2], dws + 2 * (size_t)B, B, sc.s[2]);
        dense_level_kernel<3><<<blocks, 256, 0, stream>>>(positions, Q + kOffset[3], dws + 3 * (size_t)B, B, sc.s[3]);
        dense_level_kernel<4><<<blocks, 256, 0, stream>>>(positions, Q + kOffset[4], dws + 4 * (size_t)B, B, sc.s[4]);

        for (int l = BEGIN_FAST; l < NLEVELS - 1; ++l) {
            fine_level_kernel<<<blocks, 256, 0, stream>>>(
                positions, table + kOffset[l],
                fws + (size_t)(l - BEGIN_FAST) * (size_t)B, B, sc.s[l]);
        }

        merge_final_kernel<<<blocks, 256, 0, stream>>>(
            positions, table + kOffset[15], dws, fws, out, B, sc.s[15]);
    } else {
        hash_encode_kernel<<<blocks, 256, 0, stream>>>(positions, table, out, B, sc);
    }
}

// Round 12
// 769.460 us; speedup vs baseline: 1.0742x; 1.0742x over previous
//
#include <hip/hip_runtime.h>
#include <math.h>

// InstantNGP-style hash-grid encoder, 16 levels, FEAT=2, B=2M points.
//   dense levels 0..4 (res^3 <= 2^19), hashed levels 5..15 (size = 2^19 each)
//
// Measured cost laws (r3-r11):
//   L1: divergent gathers ~127 cyc per wave-instr per CU (~1.5x at 16B) WHILE
//       the table stays on-die; off-die adds 64B/lane HBM fills.
//   L2: exec-masking / <8B payloads give no discount; 4B gathers from ws even
//       slightly slower than 8B from the input table.
//   L3: gather kernels must not stream, streaming kernels must not gather —
//       fusion evicts the table from L2 (+94us in r11, +100us in r10).
// Structure (pure recombination of each part's proven-best config):
//   - convert_quad_kernel: Q[j] = bf16x2{T[j],T[j+1],T[j+res],T[j+res+1]}
//   - 5x dense_level_kernel<L>: per-level Q slice L2-fit, 2x16B gathers/pt,
//     bf16x2 dws store (~17us each, r11)
//   - 11x fine_level_kernel: 8x8B gathers pristine f32 table, 8B f32 NT ws
//     store (51.6us each, r3)
//   - merge_kernel: pure streaming, no gathers (~75us, r8)
#define NLEVELS 16
#define BEGIN_FAST 5
#define P2 2654435761u
#define P3 805459861u
#define FAST_MASK 524287u
#define DENSE_TOTAL 330952u

constexpr unsigned kRes[NLEVELS] = {16u, 23u, 31u, 43u, 59u, 81u, 112u, 154u, 213u, 295u, 407u, 562u, 777u, 1073u, 1483u, 2048u};
constexpr unsigned kSize[NLEVELS] = {
    4096u, 12168u, 29792u, 79512u, 205384u,
    524288u, 524288u, 524288u, 524288u, 524288u, 524288u,
    524288u, 524288u, 524288u, 524288u, 524288u};
constexpr unsigned kOffset[NLEVELS] = {
    0u,       4096u,    16264u,   46056u,   125568u,  330952u,
    855240u,  1379528u, 1903816u, 2428104u, 2952392u, 3476680u,
    4000968u, 4525256u, 5049544u, 5573832u};

struct Scales {
    float s[NLEVELS];
};

typedef float fvec2 __attribute__((ext_vector_type(2)));
typedef float fvec4 __attribute__((ext_vector_type(4)));
typedef unsigned uvec4 __attribute__((ext_vector_type(4)));

// pack two f32 -> bf16x2 (round-to-nearest-even), lo = a, hi = b
__device__ __forceinline__ unsigned bfpack(float a, float b) {
    unsigned ua = __float_as_uint(a);
    unsigned ub = __float_as_uint(b);
    ua = (ua + 0x7FFFu + ((ua >> 16) & 1u)) >> 16;
    ub = (ub + 0x7FFFu + ((ub >> 16) & 1u)) & 0xFFFF0000u;
    return ua | ub;
}
__device__ __forceinline__ float bf_lo(unsigned e) { return __uint_as_float(e << 16); }
__device__ __forceinline__ float bf_hi(unsigned e) { return __uint_as_float(e & 0xFFFF0000u); }

// ---- dense quad table: Q[j] = bf16x2 of T[j], T[j+1], T[j+res], T[j+res+1] --
__global__ __launch_bounds__(256) void convert_quad_kernel(
    const float2* __restrict__ table,
    uvec4* __restrict__ Q,
    int total)
{
    int j = blockIdx.x * 256 + threadIdx.x;
    if (j >= total) return;
    int l = 0;
    if (j >= (int)kOffset[1]) l = 1;
    if (j >= (int)kOffset[2]) l = 2;
    if (j >= (int)kOffset[3]) l = 3;
    if (j >= (int)kOffset[4]) l = 4;
    const unsigned size = kSize[l];
    const unsigned res = kRes[l];
    const unsigned jl = (unsigned)j - kOffset[l];
    unsigned j1 = jl + 1u;        if (j1 >= size) j1 -= size;
    unsigned jy = jl + res;       if (jy >= size) jy -= size;
    unsigned jy1 = jy + 1u;       if (jy1 >= size) jy1 -= size;
    const float2 t0 = table[kOffset[l] + jl];
    const float2 t1 = table[kOffset[l] + j1];
    const float2 t2 = table[kOffset[l] + jy];
    const float2 t3 = table[kOffset[l] + jy1];
    uvec4 r = {bfpack(t0.x, t0.y), bfpack(t1.x, t1.y),
               bfpack(t2.x, t2.y), bfpack(t3.x, t3.y)};
    __builtin_nontemporal_store(r, Q + j);
}

// ---------------- fine (hashed) level: EXACT proven 51.6us config ------------
__global__ __launch_bounds__(256) void fine_level_kernel(
    const float* __restrict__ positions,
    const float2* __restrict__ tab,       // f32 table + level offset
    float2* __restrict__ wsl,             // ws slice [B], float2
    int B, float s)
{
    int p = blockIdx.x * 256 + threadIdx.x;
    if (p >= B) return;

    const float x = __builtin_nontemporal_load(positions + 3 * p + 0);
    const float y = __builtin_nontemporal_load(positions + 3 * p + 1);
    const float z = __builtin_nontemporal_load(positions + 3 * p + 2);

    const float px = x * s + 0.5f;
    const float py = y * s + 0.5f;
    const float pz = z * s + 0.5f;
    const float flx = floorf(px), fly = floorf(py), flz = floorf(pz);
    const float rx = px - flx, ry = py - fly, rz = pz - flz;
    const unsigned gx = (unsigned)flx;
    const unsigned gy = (unsigned)fly;
    const unsigned gz = (unsigned)flz;
    const float wx0 = 1.0f - rx, wy0 = 1.0f - ry, wz0 = 1.0f - rz;

    const unsigned hy0 = gy * P2, hy1 = hy0 + P2;
    const unsigned hz0 = gz * P3, hz1 = hz0 + P3;

    float ax = 0.0f, ay = 0.0f;
#pragma unroll
    for (int c = 0; c < 8; ++c) {
        const unsigned cx = (unsigned)(c & 1);
        const unsigned cy = (unsigned)((c >> 1) & 1);
        const unsigned cz = (unsigned)((c >> 2) & 1);
        const float w = (cx ? rx : wx0) * (cy ? ry : wy0) * (cz ? rz : wz0);
        const unsigned h = (gx + cx) ^ (cy ? hy1 : hy0) ^ (cz ? hz1 : hz0);
        const float2 t = tab[h & FAST_MASK];
        ax += w * t.x;
        ay += w * t.y;
    }
    fvec2 r = {ax, ay};
    __builtin_nontemporal_store(r, reinterpret_cast<fvec2*>(wsl) + p);
}

// ---- dense level L: per-level Q slice (L2-fit), 2x 16B gathers/pt -----------
template<int L>
__global__ __launch_bounds__(256) void dense_level_kernel(
    const float* __restrict__ positions,
    const uvec4* __restrict__ Qs,        // Q + kOffset[L]
    unsigned* __restrict__ dwsl,         // dws slice [B], bf16x2
    int B, float s)
{
    int p = blockIdx.x * 256 + threadIdx.x;
    if (p >= B) return;

    const float x = __builtin_nontemporal_load(positions + 3 * p + 0);
    const float y = __builtin_nontemporal_load(positions + 3 * p + 1);
    const float z = __builtin_nontemporal_load(positions + 3 * p + 2);

    const float px = x * s + 0.5f;
    const float py = y * s + 0.5f;
    const float pz = z * s + 0.5f;
    const float flx = floorf(px), fly = floorf(py), flz = floorf(pz);
    const float rx = px - flx, ry = py - fly, rz = pz - flz;
    const unsigned gx = (unsigned)flx;
    const unsigned gy = (unsigned)fly;
    const unsigned gz = (unsigned)flz;
    const float wx0 = 1.0f - rx, wy0 = 1.0f - ry, wz0 = 1.0f - rz;

    const unsigned res = kRes[L];
    const unsigned res2 = res * res;
    const unsigned h0 = gx + gy * res + gz * res2;

    float ax = 0.0f, ay = 0.0f;
#pragma unroll
    for (int cz = 0; cz < 2; ++cz) {
        const float wz = cz ? rz : wz0;
        const unsigned idx = (h0 + (unsigned)cz * res2) % kSize[L];
        const uvec4 q = Qs[idx];   // 16B gather: 4 (cx,cy) corners
        ax += wz * (wy0 * (wx0 * bf_lo(q.x) + rx * bf_lo(q.y)) +
                    ry  * (wx0 * bf_lo(q.z) + rx * bf_lo(q.w)));
        ay += wz * (wy0 * (wx0 * bf_hi(q.x) + rx * bf_hi(q.y)) +
                    ry  * (wx0 * bf_hi(q.z) + rx * bf_hi(q.w)));
    }
    __builtin_nontemporal_store(bfpack(ax, ay), dwsl + p);
}

// ---------------- merge: pure streaming, no gathers --------------------------
__global__ __launch_bounds__(256) void merge_kernel(
    const unsigned* __restrict__ dws,  // [5][B] bf16x2 (levels 0..4)
    const float2* __restrict__ fws,    // [11][B] float2 (levels 5..15)
    float* __restrict__ out,           // [B,32]
    int B)
{
    int p = blockIdx.x * 256 + threadIdx.x;
    if (p >= B) return;

    float o[2 * NLEVELS];
#pragma unroll
    for (int l = 0; l < BEGIN_FAST; ++l) {
        const unsigned v = __builtin_nontemporal_load(dws + (size_t)l * (size_t)B + p);
        o[2 * l + 0] = bf_lo(v);
        o[2 * l + 1] = bf_hi(v);
    }
#pragma unroll
    for (int l = BEGIN_FAST; l < NLEVELS; ++l) {
        const fvec2 v = __builtin_nontemporal_load(
            reinterpret_cast<const fvec2*>(fws) + (size_t)(l - BEGIN_FAST) * (size_t)B + p);
        o[2 * l + 0] = v.x;
        o[2 * l + 1] = v.y;
    }
    float* op = out + (size_t)p * (2 * NLEVELS);
#pragma unroll
    for (int i = 0; i < 8; ++i) {
        fvec4 v = {o[4 * i + 0], o[4 * i + 1], o[4 * i + 2], o[4 * i + 3]};
        *(reinterpret_cast<fvec4*>(op) + i) = v;
    }
}

// ---------------- fallback: monolithic f32 (if ws too small) -----------------
__global__ __launch_bounds__(256) void hash_encode_kernel(
    const float* __restrict__ positions,
    const float2* __restrict__ table,
    float* __restrict__ out,
    int B, Scales sc)
{
    int p = blockIdx.x * 256 + threadIdx.x;
    if (p >= B) return;

    const float x = positions[3 * p + 0];
    const float y = positions[3 * p + 1];
    const float z = positions[3 * p + 2];

    float o[2 * NLEVELS];

#pragma unroll
    for (int l = 0; l < NLEVELS; ++l) {
        const float s = sc.s[l];
        const float px = x * s + 0.5f;
        const float py = y * s + 0.5f;
        const float pz = z * s + 0.5f;
        const float flx = floorf(px), fly = floorf(py), flz = floorf(pz);
        const float rx = px - flx, ry = py - fly, rz = pz - flz;
        const unsigned gx = (unsigned)flx;
        const unsigned gy = (unsigned)fly;
        const unsigned gz = (unsigned)flz;
        const float wx0 = 1.0f - rx, wy0 = 1.0f - ry, wz0 = 1.0f - rz;

        float ax = 0.0f, ay = 0.0f;
#pragma unroll
        for (int c = 0; c < 8; ++c) {
            const unsigned cx = (unsigned)(c & 1);
            const unsigned cy = (unsigned)((c >> 1) & 1);
            const unsigned cz = (unsigned)((c >> 2) & 1);
            const unsigned pgx = gx + cx;
            const unsigned pgy = gy + cy;
            const unsigned pgz = gz + cz;
            const float w = (cx ? rx : wx0) * (cy ? ry : wy0) * (cz ? rz : wz0);
            unsigned h;
            if (l < BEGIN_FAST) {
                h = pgx + pgy * kRes[l] + pgz * (kRes[l] * kRes[l]);
            } else {
                h = pgx ^ (pgy * P2) ^ (pgz * P3);
            }
            const unsigned idx = (h % kSize[l]) + kOffset[l];
            const float2 t = table[idx];
            ax += w * t.x;
            ay += w * t.y;
        }
        o[2 * l + 0] = ax;
        o[2 * l + 1] = ay;
    }

    float* op = out + (size_t)p * (2 * NLEVELS);
#pragma unroll
    for (int i = 0; i < 8; ++i) {
        fvec4 v = {o[4 * i + 0], o[4 * i + 1], o[4 * i + 2], o[4 * i + 3]};
        *(reinterpret_cast<fvec4*>(op) + i) = v;
    }
}

extern "C" void kernel_launch(void* const* d_in, const int* in_sizes, int n_in,
                              void* d_out, int out_size, void* d_ws, size_t ws_size,
                              hipStream_t stream) {
    const float* positions = (const float*)d_in[0];
    const float2* table = (const float2*)d_in[1];
    float* out = (float*)d_out;

    const int B = in_sizes[0] / 3;

    Scales sc;
    const double log_b = log(2048.0 / 16.0) / (NLEVELS - 1);
    for (int l = 0; l < NLEVELS; ++l) {
        sc.s[l] = (float)(16.0 * exp((double)l * log_b) - 1.0);
    }

    const int blocks = (B + 255) / 256;

    // ws layout: [5 dense slices u32][11 fine slices float2][quad table Q]
    const size_t dws_bytes = 5u * (size_t)B * sizeof(unsigned);       // 40 MB
    const size_t fws_bytes = 11u * (size_t)B * sizeof(float2);        // 176 MB
    const size_t Q_bytes = (size_t)DENSE_TOTAL * sizeof(uvec4);       // 5.3 MB
    const size_t ws_need = dws_bytes + fws_bytes + Q_bytes;

    if (ws_size >= ws_need) {
        unsigned* dws = (unsigned*)d_ws;
        float2* fws = (float2*)((char*)d_ws + dws_bytes);
        uvec4* Q = (uvec4*)((char*)d_ws + dws_bytes + fws_bytes);

        convert_quad_kernel<<<((int)DENSE_TOTAL + 255) / 256, 256, 0, stream>>>(
            table, Q, (int)DENSE_TOTAL);

        dense_level_kernel<0><<<blocks, 256, 0, stream>>>(positions, Q + kOffset[0], dws + 0 * (size_t)B, B, sc.s[0]);
        dense_level_kernel<1><<<blocks, 256, 0, stream>>>(positions, Q + kOffset[1], dws + 1 * (size_t)B, B, sc.s[1]);
        dense_level_kernel<2><<<blocks, 256, 0, stream>>>(positions, Q + kOffset[2], dws + 2 * (size_t)B, B, sc.s[2]);
        dense_level_kernel<3><<<blocks, 256, 0, stream>>>(positions, Q + kOffset[3], dws + 3 * (size_t)B, B, sc.s[3]);
        dense_level_kernel<4><<<blocks, 256, 0, stream>>>(positions, Q + kOffset[4], dws + 4 * (size_t)B, B, sc.s[4]);

        for (int l = BEGIN_FAST; l < NLEVELS; ++l) {
            fine_level_kernel<<<blocks, 256, 0, stream>>>(
                positions, table + kOffset[l],
                fws + (size_t)(l - BEGIN_FAST) * (size_t)B, B, sc.s[l]);
        }

        merge_kernel<<<blocks, 256, 0, stream>>>(dws, fws, out, B);
    } else {
        hash_encode_kernel<<<blocks, 256, 0, stream>>>(positions, table, out, B, sc);
    }
}

// Round 13
// 764.247 us; speedup vs baseline: 1.0815x; 1.0068x over previous
//
#include <hip/hip_runtime.h>
#include <math.h>

// InstantNGP-style hash-grid encoder, 16 levels, FEAT=2, B=2M points.
//   dense levels 0..4 (res^3 <= 2^19), hashed levels 5..15 (size = 2^19 each)
//
// Measured cost laws (r3-r12):
//   L1: divergent gathers cost ~127 cyc (<=8B) / ~167 cyc (16B) per
//       wave-instruction per CU while the table is on-die; FLAT in active-lane
//       count, cache level, and address uniqueness. Fine = 8 instr x 127 cyc
//       x 122 waves/CU = 51.7us/level (exact match).
//   L2: stores & streaming in gather kernels hide under gather time.
//   L3: gather kernels must not stream large buffers; streaming kernels must
//       not gather (L2 eviction, +94us r11).
// Structure:
//   - convert_quad_kernel: Q[j] = bf16x2{T[j],T[j+1],T[j+res],T[j+res+1]}
//   - 5x dense_level_kernel<L>: per-level Q slice L2-fit, 2x16B gathers/pt
//   - 11x fine_level_kernel: 8x8B gathers pristine f32 table, bf16x2 ws store
//   - merge_kernel: pure streaming; ws (128MB) is L3-resident
#define NLEVELS 16
#define BEGIN_FAST 5
#define P2 2654435761u
#define P3 805459861u
#define FAST_MASK 524287u
#define DENSE_TOTAL 330952u

constexpr unsigned kRes[NLEVELS] = {16u, 23u, 31u, 43u, 59u, 81u, 112u, 154u, 213u, 295u, 407u, 562u, 777u, 1073u, 1483u, 2048u};
constexpr unsigned kSize[NLEVELS] = {
    4096u, 12168u, 29792u, 79512u, 205384u,
    524288u, 524288u, 524288u, 524288u, 524288u, 524288u,
    524288u, 524288u, 524288u, 524288u, 524288u};
constexpr unsigned kOffset[NLEVELS] = {
    0u,       4096u,    16264u,   46056u,   125568u,  330952u,
    855240u,  1379528u, 1903816u, 2428104u, 2952392u, 3476680u,
    4000968u, 4525256u, 5049544u, 5573832u};

struct Scales {
    float s[NLEVELS];
};

typedef float fvec2 __attribute__((ext_vector_type(2)));
typedef float fvec4 __attribute__((ext_vector_type(4)));
typedef unsigned uvec4 __attribute__((ext_vector_type(4)));

// pack two f32 -> bf16x2 (round-to-nearest-even), lo = a, hi = b
__device__ __forceinline__ unsigned bfpack(float a, float b) {
    unsigned ua = __float_as_uint(a);
    unsigned ub = __float_as_uint(b);
    ua = (ua + 0x7FFFu + ((ua >> 16) & 1u)) >> 16;
    ub = (ub + 0x7FFFu + ((ub >> 16) & 1u)) & 0xFFFF0000u;
    return ua | ub;
}
__device__ __forceinline__ float bf_lo(unsigned e) { return __uint_as_float(e << 16); }
__device__ __forceinline__ float bf_hi(unsigned e) { return __uint_as_float(e & 0xFFFF0000u); }

// ---- dense quad table: Q[j] = bf16x2 of T[j], T[j+1], T[j+res], T[j+res+1] --
__global__ __launch_bounds__(256) void convert_quad_kernel(
    const float2* __restrict__ table,
    uvec4* __restrict__ Q,
    int total)
{
    int j = blockIdx.x * 256 + threadIdx.x;
    if (j >= total) return;
    int l = 0;
    if (j >= (int)kOffset[1]) l = 1;
    if (j >= (int)kOffset[2]) l = 2;
    if (j >= (int)kOffset[3]) l = 3;
    if (j >= (int)kOffset[4]) l = 4;
    const unsigned size = kSize[l];
    const unsigned res = kRes[l];
    const unsigned jl = (unsigned)j - kOffset[l];
    unsigned j1 = jl + 1u;        if (j1 >= size) j1 -= size;
    unsigned jy = jl + res;       if (jy >= size) jy -= size;
    unsigned jy1 = jy + 1u;       if (jy1 >= size) jy1 -= size;
    const float2 t0 = table[kOffset[l] + jl];
    const float2 t1 = table[kOffset[l] + j1];
    const float2 t2 = table[kOffset[l] + jy];
    const float2 t3 = table[kOffset[l] + jy1];
    uvec4 r = {bfpack(t0.x, t0.y), bfpack(t1.x, t1.y),
               bfpack(t2.x, t2.y), bfpack(t3.x, t3.y)};
    __builtin_nontemporal_store(r, Q + j);
}

// ------- fine (hashed) level: 8x8B pristine-table gathers, bf16 ws store -----
__global__ __launch_bounds__(256) void fine_level_kernel(
    const float* __restrict__ positions,
    const float2* __restrict__ tab,       // f32 table + level offset
    unsigned* __restrict__ wsl,           // ws slice [B], bf16x2
    int B, float s)
{
    int p = blockIdx.x * 256 + threadIdx.x;
    if (p >= B) return;

    const float x = __builtin_nontemporal_load(positions + 3 * p + 0);
    const float y = __builtin_nontemporal_load(positions + 3 * p + 1);
    const float z = __builtin_nontemporal_load(positions + 3 * p + 2);

    const float px = x * s + 0.5f;
    const float py = y * s + 0.5f;
    const float pz = z * s + 0.5f;
    const float flx = floorf(px), fly = floorf(py), flz = floorf(pz);
    const float rx = px - flx, ry = py - fly, rz = pz - flz;
    const unsigned gx = (unsigned)flx;
    const unsigned gy = (unsigned)fly;
    const unsigned gz = (unsigned)flz;
    const float wx0 = 1.0f - rx, wy0 = 1.0f - ry, wz0 = 1.0f - rz;

    const unsigned hy0 = gy * P2, hy1 = hy0 + P2;
    const unsigned hz0 = gz * P3, hz1 = hz0 + P3;

    float ax = 0.0f, ay = 0.0f;
#pragma unroll
    for (int c = 0; c < 8; ++c) {
        const unsigned cx = (unsigned)(c & 1);
        const unsigned cy = (unsigned)((c >> 1) & 1);
        const unsigned cz = (unsigned)((c >> 2) & 1);
        const float w = (cx ? rx : wx0) * (cy ? ry : wy0) * (cz ? rz : wz0);
        const unsigned h = (gx + cx) ^ (cy ? hy1 : hy0) ^ (cz ? hz1 : hz0);
        const float2 t = tab[h & FAST_MASK];
        ax += w * t.x;
        ay += w * t.y;
    }
    __builtin_nontemporal_store(bfpack(ax, ay), wsl + p);
}

// ---- dense level L: per-level Q slice (L2-fit), 2x 16B gathers/pt -----------
template<int L>
__global__ __launch_bounds__(256) void dense_level_kernel(
    const float* __restrict__ positions,
    const uvec4* __restrict__ Qs,        // Q + kOffset[L]
    unsigned* __restrict__ dwsl,         // dws slice [B], bf16x2
    int B, float s)
{
    int p = blockIdx.x * 256 + threadIdx.x;
    if (p >= B) return;

    const float x = __builtin_nontemporal_load(positions + 3 * p + 0);
    const float y = __builtin_nontemporal_load(positions + 3 * p + 1);
    const float z = __builtin_nontemporal_load(positions + 3 * p + 2);

    const float px = x * s + 0.5f;
    const float py = y * s + 0.5f;
    const float pz = z * s + 0.5f;
    const float flx = floorf(px), fly = floorf(py), flz = floorf(pz);
    const float rx = px - flx, ry = py - fly, rz = pz - flz;
    const unsigned gx = (unsigned)flx;
    const unsigned gy = (unsigned)fly;
    const unsigned gz = (unsigned)flz;
    const float wx0 = 1.0f - rx, wy0 = 1.0f - ry, wz0 = 1.0f - rz;

    const unsigned res = kRes[L];
    const unsigned res2 = res * res;
    const unsigned h0 = gx + gy * res + gz * res2;

    float ax = 0.0f, ay = 0.0f;
#pragma unroll
    for (int cz = 0; cz < 2; ++cz) {
        const float wz = cz ? rz : wz0;
        const unsigned idx = (h0 + (unsigned)cz * res2) % kSize[L];
        const uvec4 q = Qs[idx];   // 16B gather: 4 (cx,cy) corners
        ax += wz * (wy0 * (wx0 * bf_lo(q.x) + rx * bf_lo(q.y)) +
                    ry  * (wx0 * bf_lo(q.z) + rx * bf_lo(q.w)));
        ay += wz * (wy0 * (wx0 * bf_hi(q.x) + rx * bf_hi(q.y)) +
                    ry  * (wx0 * bf_hi(q.z) + rx * bf_hi(q.w)));
    }
    __builtin_nontemporal_store(bfpack(ax, ay), dwsl + p);
}

// ---------------- merge: pure streaming, no gathers --------------------------
__global__ __launch_bounds__(256) void merge_kernel(
    const unsigned* __restrict__ dws,  // [5][B] bf16x2 (levels 0..4)
    const unsigned* __restrict__ fws,  // [11][B] bf16x2 (levels 5..15)
    float* __restrict__ out,           // [B,32]
    int B)
{
    int p = blockIdx.x * 256 + threadIdx.x;
    if (p >= B) return;

    float o[2 * NLEVELS];
#pragma unroll
    for (int l = 0; l < BEGIN_FAST; ++l) {
        const unsigned v = __builtin_nontemporal_load(dws + (size_t)l * (size_t)B + p);
        o[2 * l + 0] = bf_lo(v);
        o[2 * l + 1] = bf_hi(v);
    }
#pragma unroll
    for (int l = BEGIN_FAST; l < NLEVELS; ++l) {
        const unsigned v = __builtin_nontemporal_load(
            fws + (size_t)(l - BEGIN_FAST) * (size_t)B + p);
        o[2 * l + 0] = bf_lo(v);
        o[2 * l + 1] = bf_hi(v);
    }
    float* op = out + (size_t)p * (2 * NLEVELS);
#pragma unroll
    for (int i = 0; i < 8; ++i) {
        fvec4 v = {o[4 * i + 0], o[4 * i + 1], o[4 * i + 2], o[4 * i + 3]};
        *(reinterpret_cast<fvec4*>(op) + i) = v;
    }
}

// ---------------- fallback: monolithic f32 (if ws too small) -----------------
__global__ __launch_bounds__(256) void hash_encode_kernel(
    const float* __restrict__ positions,
    const float2* __restrict__ table,
    float* __restrict__ out,
    int B, Scales sc)
{
    int p = blockIdx.x * 256 + threadIdx.x;
    if (p >= B) return;

    const float x = positions[3 * p + 0];
    const float y = positions[3 * p + 1];
    const float z = positions[3 * p + 2];

    float o[2 * NLEVELS];

#pragma unroll
    for (int l = 0; l < NLEVELS; ++l) {
        const float s = sc.s[l];
        const float px = x * s + 0.5f;
        const float py = y * s + 0.5f;
        const float pz = z * s + 0.5f;
        const float flx = floorf(px), fly = floorf(py), flz = floorf(pz);
        const float rx = px - flx, ry = py - fly, rz = pz - flz;
        const unsigned gx = (unsigned)flx;
        const unsigned gy = (unsigned)fly;
        const unsigned gz = (unsigned)flz;
        const float wx0 = 1.0f - rx, wy0 = 1.0f - ry, wz0 = 1.0f - rz;

        float ax = 0.0f, ay = 0.0f;
#pragma unroll
        for (int c = 0; c < 8; ++c) {
            const unsigned cx = (unsigned)(c & 1);
            const unsigned cy = (unsigned)((c >> 1) & 1);
            const unsigned cz = (unsigned)((c >> 2) & 1);
            const unsigned pgx = gx + cx;
            const unsigned pgy = gy + cy;
            const unsigned pgz = gz + cz;
            const float w = (cx ? rx : wx0) * (cy ? ry : wy0) * (cz ? rz : wz0);
            unsigned h;
            if (l < BEGIN_FAST) {
                h = pgx + pgy * kRes[l] + pgz * (kRes[l] * kRes[l]);
            } else {
                h = pgx ^ (pgy * P2) ^ (pgz * P3);
            }
            const unsigned idx = (h % kSize[l]) + kOffset[l];
            const float2 t = table[idx];
            ax += w * t.x;
            ay += w * t.y;
        }
        o[2 * l + 0] = ax;
        o[2 * l + 1] = ay;
    }

    float* op = out + (size_t)p * (2 * NLEVELS);
#pragma unroll
    for (int i = 0; i < 8; ++i) {
        fvec4 v = {o[4 * i + 0], o[4 * i + 1], o[4 * i + 2], o[4 * i + 3]};
        *(reinterpret_cast<fvec4*>(op) + i) = v;
    }
}

extern "C" void kernel_launch(void* const* d_in, const int* in_sizes, int n_in,
                              void* d_out, int out_size, void* d_ws, size_t ws_size,
                              hipStream_t stream) {
    const float* positions = (const float*)d_in[0];
    const float2* table = (const float2*)d_in[1];
    float* out = (float*)d_out;

    const int B = in_sizes[0] / 3;

    Scales sc;
    const double log_b = log(2048.0 / 16.0) / (NLEVELS - 1);
    for (int l = 0; l < NLEVELS; ++l) {
        sc.s[l] = (float)(16.0 * exp((double)l * log_b) - 1.0);
    }

    const int blocks = (B + 255) / 256;

    // ws layout: [5 dense slices u32][11 fine slices u32][quad table Q]
    const size_t dws_bytes = 5u * (size_t)B * sizeof(unsigned);       // 40 MB
    const size_t fws_bytes = 11u * (size_t)B * sizeof(unsigned);      // 88 MB
    const size_t Q_bytes = (size_t)DENSE_TOTAL * sizeof(uvec4);       // 5.3 MB
    const size_t ws_need = dws_bytes + fws_bytes + Q_bytes;

    if (ws_size >= ws_need) {
        unsigned* dws = (unsigned*)d_ws;
        unsigned* fws = (unsigned*)((char*)d_ws + dws_bytes);
        uvec4* Q = (uvec4*)((char*)d_ws + dws_bytes + fws_bytes);

        convert_quad_kernel<<<((int)DENSE_TOTAL + 255) / 256, 256, 0, stream>>>(
            table, Q, (int)DENSE_TOTAL);

        dense_level_kernel<0><<<blocks, 256, 0, stream>>>(positions, Q + kOffset[0], dws + 0 * (size_t)B, B, sc.s[0]);
        dense_level_kernel<1><<<blocks, 256, 0, stream>>>(positions, Q + kOffset[1], dws + 1 * (size_t)B, B, sc.s[1]);
        dense_level_kernel<2><<<blocks, 256, 0, stream>>>(positions, Q + kOffset[2], dws + 2 * (size_t)B, B, sc.s[2]);
        dense_level_kernel<3><<<blocks, 256, 0, stream>>>(positions, Q + kOffset[3], dws + 3 * (size_t)B, B, sc.s[3]);
        dense_level_kernel<4><<<blocks, 256, 0, stream>>>(positions, Q + kOffset[4], dws + 4 * (size_t)B, B, sc.s[4]);

        for (int l = BEGIN_FAST; l < NLEVELS; ++l) {
            fine_level_kernel<<<blocks, 256, 0, stream>>>(
                positions, table + kOffset[l],
                fws + (size_t)(l - BEGIN_FAST) * (size_t)B, B, sc.s[l]);
        }

        merge_kernel<<<blocks, 256, 0, stream>>>(dws, fws, out, B);
    } else {
        hash_encode_kernel<<<blocks, 256, 0, stream>>>(positions, table, out, B, sc);
    }
}

// Round 14
// 730.966 us; speedup vs baseline: 1.1308x; 1.0455x over previous
//
#include <hip/hip_runtime.h>
#include <math.h>

// InstantNGP-style hash-grid encoder, 16 levels, FEAT=2, B=2M points.
//   dense levels 0..4 (res^3 <= 2^19), hashed levels 5..15 (size = 2^19 each)
//
// Measured cost laws (r3-r13):
//   L1: divergent gathers cost ~127 cyc (<=8B) / ~167 cyc (16B) per
//       wave-instruction per CU while the table is on-die; FLAT in active-lane
//       count and address uniqueness. Fine = 8 x 127 x 122 waves/CU = 51.7us
//       per level (exact). Dense = 2 x 167 x 122 = 17us/level (exact).
//   L2: stores & position streams hide under gather time; bf16 ws stores free.
//   L3: gather kernels must not stream big buffers and vice versa (L2 evict).
//   L4: ~3us per launch + tail drain => 17 launches cost ~50us (this round's
//       target): fuse all 16 compute kernels into one 2D-grid mega-kernel,
//       blockIdx.y = level (x-fastest dispatch keeps 1-2 slices per L2).
#define NLEVELS 16
#define BEGIN_FAST 5
#define P2 2654435761u
#define P3 805459861u
#define FAST_MASK 524287u
#define DENSE_TOTAL 330952u

constexpr unsigned kRes[NLEVELS] = {16u, 23u, 31u, 43u, 59u, 81u, 112u, 154u, 213u, 295u, 407u, 562u, 777u, 1073u, 1483u, 2048u};
constexpr unsigned kSize[NLEVELS] = {
    4096u, 12168u, 29792u, 79512u, 205384u,
    524288u, 524288u, 524288u, 524288u, 524288u, 524288u,
    524288u, 524288u, 524288u, 524288u, 524288u};
constexpr unsigned kOffset[NLEVELS] = {
    0u,       4096u,    16264u,   46056u,   125568u,  330952u,
    855240u,  1379528u, 1903816u, 2428104u, 2952392u, 3476680u,
    4000968u, 4525256u, 5049544u, 5573832u};

struct Scales {
    float s[NLEVELS];
};

typedef float fvec4 __attribute__((ext_vector_type(4)));
typedef unsigned uvec4 __attribute__((ext_vector_type(4)));

// pack two f32 -> bf16x2 (round-to-nearest-even), lo = a, hi = b
__device__ __forceinline__ unsigned bfpack(float a, float b) {
    unsigned ua = __float_as_uint(a);
    unsigned ub = __float_as_uint(b);
    ua = (ua + 0x7FFFu + ((ua >> 16) & 1u)) >> 16;
    ub = (ub + 0x7FFFu + ((ub >> 16) & 1u)) & 0xFFFF0000u;
    return ua | ub;
}
__device__ __forceinline__ float bf_lo(unsigned e) { return __uint_as_float(e << 16); }
__device__ __forceinline__ float bf_hi(unsigned e) { return __uint_as_float(e & 0xFFFF0000u); }

// ---- dense quad table: Q[j] = bf16x2 of T[j], T[j+1], T[j+res], T[j+res+1] --
__global__ __launch_bounds__(256) void convert_quad_kernel(
    const float2* __restrict__ table,
    uvec4* __restrict__ Q,
    int total)
{
    int j = blockIdx.x * 256 + threadIdx.x;
    if (j >= total) return;
    int l = 0;
    if (j >= (int)kOffset[1]) l = 1;
    if (j >= (int)kOffset[2]) l = 2;
    if (j >= (int)kOffset[3]) l = 3;
    if (j >= (int)kOffset[4]) l = 4;
    const unsigned size = kSize[l];
    const unsigned res = kRes[l];
    const unsigned jl = (unsigned)j - kOffset[l];
    unsigned j1 = jl + 1u;        if (j1 >= size) j1 -= size;
    unsigned jy = jl + res;       if (jy >= size) jy -= size;
    unsigned jy1 = jy + 1u;       if (jy1 >= size) jy1 -= size;
    const float2 t0 = table[kOffset[l] + jl];
    const float2 t1 = table[kOffset[l] + j1];
    const float2 t2 = table[kOffset[l] + jy];
    const float2 t3 = table[kOffset[l] + jy1];
    uvec4 r = {bfpack(t0.x, t0.y), bfpack(t1.x, t1.y),
               bfpack(t2.x, t2.y), bfpack(t3.x, t3.y)};
    __builtin_nontemporal_store(r, Q + j);
}

// ------- fine body (level L): 8x8B pristine-table gathers, bf16 ws store -----
template<int L>
__device__ __forceinline__ void fine_body(
    const float* __restrict__ positions,
    const float2* __restrict__ table,
    unsigned* __restrict__ fws,
    int B, int p, float s)
{
    const float x = __builtin_nontemporal_load(positions + 3 * p + 0);
    const float y = __builtin_nontemporal_load(positions + 3 * p + 1);
    const float z = __builtin_nontemporal_load(positions + 3 * p + 2);

    const float px = x * s + 0.5f;
    const float py = y * s + 0.5f;
    const float pz = z * s + 0.5f;
    const float flx = floorf(px), fly = floorf(py), flz = floorf(pz);
    const float rx = px - flx, ry = py - fly, rz = pz - flz;
    const unsigned gx = (unsigned)flx;
    const unsigned gy = (unsigned)fly;
    const unsigned gz = (unsigned)flz;
    const float wx0 = 1.0f - rx, wy0 = 1.0f - ry, wz0 = 1.0f - rz;

    const float2* tab = table + kOffset[L];
    const unsigned hy0 = gy * P2, hy1 = hy0 + P2;
    const unsigned hz0 = gz * P3, hz1 = hz0 + P3;

    float ax = 0.0f, ay = 0.0f;
#pragma unroll
    for (int c = 0; c < 8; ++c) {
        const unsigned cx = (unsigned)(c & 1);
        const unsigned cy = (unsigned)((c >> 1) & 1);
        const unsigned cz = (unsigned)((c >> 2) & 1);
        const float w = (cx ? rx : wx0) * (cy ? ry : wy0) * (cz ? rz : wz0);
        const unsigned h = (gx + cx) ^ (cy ? hy1 : hy0) ^ (cz ? hz1 : hz0);
        const float2 t = tab[h & FAST_MASK];
        ax += w * t.x;
        ay += w * t.y;
    }
    __builtin_nontemporal_store(bfpack(ax, ay),
        fws + (size_t)(L - BEGIN_FAST) * (size_t)B + p);
}

// ---- dense body (level L): quad-table slice, 2x16B gathers ------------------
template<int L>
__device__ __forceinline__ void dense_body(
    const float* __restrict__ positions,
    const uvec4* __restrict__ Q,
    unsigned* __restrict__ dws,
    int B, int p, float s)
{
    const float x = __builtin_nontemporal_load(positions + 3 * p + 0);
    const float y = __builtin_nontemporal_load(positions + 3 * p + 1);
    const float z = __builtin_nontemporal_load(positions + 3 * p + 2);

    const float px = x * s + 0.5f;
    const float py = y * s + 0.5f;
    const float pz = z * s + 0.5f;
    const float flx = floorf(px), fly = floorf(py), flz = floorf(pz);
    const float rx = px - flx, ry = py - fly, rz = pz - flz;
    const unsigned gx = (unsigned)flx;
    const unsigned gy = (unsigned)fly;
    const unsigned gz = (unsigned)flz;
    const float wx0 = 1.0f - rx, wy0 = 1.0f - ry, wz0 = 1.0f - rz;

    const uvec4* Qs = Q + kOffset[L];
    const unsigned res = kRes[L];
    const unsigned res2 = res * res;
    const unsigned h0 = gx + gy * res + gz * res2;

    float ax = 0.0f, ay = 0.0f;
#pragma unroll
    for (int cz = 0; cz < 2; ++cz) {
        const float wz = cz ? rz : wz0;
        const unsigned idx = (h0 + (unsigned)cz * res2) % kSize[L];
        const uvec4 q = Qs[idx];   // 16B gather: 4 (cx,cy) corners
        ax += wz * (wy0 * (wx0 * bf_lo(q.x) + rx * bf_lo(q.y)) +
                    ry  * (wx0 * bf_lo(q.z) + rx * bf_lo(q.w)));
        ay += wz * (wy0 * (wx0 * bf_hi(q.x) + rx * bf_hi(q.y)) +
                    ry  * (wx0 * bf_hi(q.z) + rx * bf_hi(q.w)));
    }
    __builtin_nontemporal_store(bfpack(ax, ay), dws + (size_t)L * (size_t)B + p);
}

// ---- mega: all 16 levels in one dispatch; blockIdx.y = level group ----------
// y = 0..10 -> fine levels 5..15 (long work first); y = 11..15 -> dense 0..4.
__global__ __launch_bounds__(256) void mega_kernel(
    const float* __restrict__ positions,
    const float2* __restrict__ table,
    const uvec4* __restrict__ Q,
    unsigned* __restrict__ dws,
    unsigned* __restrict__ fws,
    int B, Scales sc)
{
    const int p = blockIdx.x * 256 + threadIdx.x;
    if (p >= B) return;

    switch (blockIdx.y) {
    case 0:  fine_body<5>(positions, table, fws, B, p, sc.s[5]);  break;
    case 1:  fine_body<6>(positions, table, fws, B, p, sc.s[6]);  break;
    case 2:  fine_body<7>(positions, table, fws, B, p, sc.s[7]);  break;
    case 3:  fine_body<8>(positions, table, fws, B, p, sc.s[8]);  break;
    case 4:  fine_body<9>(positions, table, fws, B, p, sc.s[9]);  break;
    case 5:  fine_body<10>(positions, table, fws, B, p, sc.s[10]); break;
    case 6:  fine_body<11>(positions, table, fws, B, p, sc.s[11]); break;
    case 7:  fine_body<12>(positions, table, fws, B, p, sc.s[12]); break;
    case 8:  fine_body<13>(positions, table, fws, B, p, sc.s[13]); break;
    case 9:  fine_body<14>(positions, table, fws, B, p, sc.s[14]); break;
    case 10: fine_body<15>(positions, table, fws, B, p, sc.s[15]); break;
    case 11: dense_body<0>(positions, Q, dws, B, p, sc.s[0]); break;
    case 12: dense_body<1>(positions, Q, dws, B, p, sc.s[1]); break;
    case 13: dense_body<2>(positions, Q, dws, B, p, sc.s[2]); break;
    case 14: dense_body<3>(positions, Q, dws, B, p, sc.s[3]); break;
    default: dense_body<4>(positions, Q, dws, B, p, sc.s[4]); break;
    }
}

// ---------------- merge: pure streaming, no gathers --------------------------
__global__ __launch_bounds__(256) void merge_kernel(
    const unsigned* __restrict__ dws,  // [5][B] bf16x2 (levels 0..4)
    const unsigned* __restrict__ fws,  // [11][B] bf16x2 (levels 5..15)
    float* __restrict__ out,           // [B,32]
    int B)
{
    int p = blockIdx.x * 256 + threadIdx.x;
    if (p >= B) return;

    float o[2 * NLEVELS];
#pragma unroll
    for (int l = 0; l < BEGIN_FAST; ++l) {
        const unsigned v = __builtin_nontemporal_load(dws + (size_t)l * (size_t)B + p);
        o[2 * l + 0] = bf_lo(v);
        o[2 * l + 1] = bf_hi(v);
    }
#pragma unroll
    for (int l = BEGIN_FAST; l < NLEVELS; ++l) {
        const unsigned v = __builtin_nontemporal_load(
            fws + (size_t)(l - BEGIN_FAST) * (size_t)B + p);
        o[2 * l + 0] = bf_lo(v);
        o[2 * l + 1] = bf_hi(v);
    }
    float* op = out + (size_t)p * (2 * NLEVELS);
#pragma unroll
    for (int i = 0; i < 8; ++i) {
        fvec4 v = {o[4 * i + 0], o[4 * i + 1], o[4 * i + 2], o[4 * i + 3]};
        *(reinterpret_cast<fvec4*>(op) + i) = v;
    }
}

// ---------------- fallback: monolithic f32 (if ws too small) -----------------
__global__ __launch_bounds__(256) void hash_encode_kernel(
    const float* __restrict__ positions,
    const float2* __restrict__ table,
    float* __restrict__ out,
    int B, Scales sc)
{
    int p = blockIdx.x * 256 + threadIdx.x;
    if (p >= B) return;

    const float x = positions[3 * p + 0];
    const float y = positions[3 * p + 1];
    const float z = positions[3 * p + 2];

    float o[2 * NLEVELS];

#pragma unroll
    for (int l = 0; l < NLEVELS; ++l) {
        const float s = sc.s[l];
        const float px = x * s + 0.5f;
        const float py = y * s + 0.5f;
        const float pz = z * s + 0.5f;
        const float flx = floorf(px), fly = floorf(py), flz = floorf(pz);
        const float rx = px - flx, ry = py - fly, rz = pz - flz;
        const unsigned gx = (unsigned)flx;
        const unsigned gy = (unsigned)fly;
        const unsigned gz = (unsigned)flz;
        const float wx0 = 1.0f - rx, wy0 = 1.0f - ry, wz0 = 1.0f - rz;

        float ax = 0.0f, ay = 0.0f;
#pragma unroll
        for (int c = 0; c < 8; ++c) {
            const unsigned cx = (unsigned)(c & 1);
            const unsigned cy = (unsigned)((c >> 1) & 1);
            const unsigned cz = (unsigned)((c >> 2) & 1);
            const unsigned pgx = gx + cx;
            const unsigned pgy = gy + cy;
            const unsigned pgz = gz + cz;
            const float w = (cx ? rx : wx0) * (cy ? ry : wy0) * (cz ? rz : wz0);
            unsigned h;
            if (l < BEGIN_FAST) {
                h = pgx + pgy * kRes[l] + pgz * (kRes[l] * kRes[l]);
            } else {
                h = pgx ^ (pgy * P2) ^ (pgz * P3);
            }
            const unsigned idx = (h % kSize[l]) + kOffset[l];
            const float2 t = table[idx];
            ax += w * t.x;
            ay += w * t.y;
        }
        o[2 * l + 0] = ax;
        o[2 * l + 1] = ay;
    }

    float* op = out + (size_t)p * (2 * NLEVELS);
#pragma unroll
    for (int i = 0; i < 8; ++i) {
        fvec4 v = {o[4 * i + 0], o[4 * i + 1], o[4 * i + 2], o[4 * i + 3]};
        *(reinterpret_cast<fvec4*>(op) + i) = v;
    }
}

extern "C" void kernel_launch(void* const* d_in, const int* in_sizes, int n_in,
                              void* d_out, int out_size, void* d_ws, size_t ws_size,
                              hipStream_t stream) {
    const float* positions = (const float*)d_in[0];
    const float2* table = (const float2*)d_in[1];
    float* out = (float*)d_out;

    const int B = in_sizes[0] / 3;

    Scales sc;
    const double log_b = log(2048.0 / 16.0) / (NLEVELS - 1);
    for (int l = 0; l < NLEVELS; ++l) {
        sc.s[l] = (float)(16.0 * exp((double)l * log_b) - 1.0);
    }

    const int blocks = (B + 255) / 256;

    // ws layout: [5 dense slices u32][11 fine slices u32][quad table Q]
    const size_t dws_bytes = 5u * (size_t)B * sizeof(unsigned);       // 40 MB
    const size_t fws_bytes = 11u * (size_t)B * sizeof(unsigned);      // 88 MB
    const size_t Q_bytes = (size_t)DENSE_TOTAL * sizeof(uvec4);       // 5.3 MB
    const size_t ws_need = dws_bytes + fws_bytes + Q_bytes;

    if (ws_size >= ws_need) {
        unsigned* dws = (unsigned*)d_ws;
        unsigned* fws = (unsigned*)((char*)d_ws + dws_bytes);
        uvec4* Q = (uvec4*)((char*)d_ws + dws_bytes + fws_bytes);

        convert_quad_kernel<<<((int)DENSE_TOTAL + 255) / 256, 256, 0, stream>>>(
            table, Q, (int)DENSE_TOTAL);

        dim3 grid((unsigned)blocks, 16u, 1u);
        mega_kernel<<<grid, 256, 0, stream>>>(positions, table, Q, dws, fws, B, sc);

        merge_kernel<<<blocks, 256, 0, stream>>>(dws, fws, out, B);
    } else {
        hash_encode_kernel<<<blocks, 256, 0, stream>>>(positions, table, out, B, sc);
    }
}